// Round 26
// baseline (33413.086 us; speedup 1.0000x reference)
//
#include <hip/hip_runtime.h>

#define LOG2E 1.44269504088896340736f

__device__ __forceinline__ float lrelu(float z) { return fmaxf(z, 0.01f * z); }
__device__ __forceinline__ float sigf(float z) {
    float p = __builtin_amdgcn_exp2f(-LOG2E * z);
    return __builtin_amdgcn_rcpf(1.0f + p);
}

#define WQ(i) __int_as_float(__builtin_amdgcn_readlane(__float_as_int(wreg[(i) >> 6]), (i) & 63))

// ====== PC-v6: PC-v5 + 240-float AGPR pin per wave ======
// R25: 3.55ms; LDS pipe ~10.3K of 17.7K cyc/step (binding + queueing);
// VGPR_Count=116 shows "+v" pin partially defeated. gfx950 unified file:
// 256 VGPR + 256 AGPR per wave at 1 wave/SIMD; VALU reads AGPR directly.
// Pin 240 floats/wave in AGPRs (asm "+a") -> zero per-step cost, offloads
// 60 rows of uniform ds_read: LDS/CU-step 860 -> 620 f4 (~7.4K cyc).
//   F: LDS rows 0..24 | AGPR rows 25..36 | VGPR rows 37..43 | RL rest (332)
//   X: LDS rows 0..26 + trip | AGPR rows 27..38 | VGPR rows 39..45 | RL 142
__global__ void __launch_bounds__(256, 1)
pc6_kernel(const float* __restrict__ w,
           const float* __restrict__ Wh1, const float* __restrict__ bh1,
           const float* __restrict__ Wh2, const float* __restrict__ bh2,
           const float* __restrict__ Wh3, const float* __restrict__ bh3,
           const float* __restrict__ Wx1, const float* __restrict__ bx1,
           const float* __restrict__ Wx2, const float* __restrict__ bx2,
           const float* __restrict__ Wx3, const float* __restrict__ bx3,
           float2* __restrict__ out, int B, int T)
{
    __shared__ float4 sW2h[125];       // Wh2 rows 0..24
    __shared__ float4 sW2x[135];       // Wx2 rows 0..26
    __shared__ float4 sL1x[50];        // (Wx1[0][k], Wx1[1][k], bx1[k], 0)
    __shared__ float2 hbuf[2][256];    // double-buffered h handoff

    {
        float* a = (float*)sW2h;
        for (int i = threadIdx.x; i < 500; i += 256) a[i] = Wh2[i];
        float* b = (float*)sW2x;
        for (int i = threadIdx.x; i < 540; i += 256) b[i] = Wx2[i];
        if (threadIdx.x < 50)
            sL1x[threadIdx.x] = make_float4(Wx1[threadIdx.x], Wx1[50 + threadIdx.x],
                                            bx1[threadIdx.x], 0.f);
    }

    const int wid  = threadIdx.x >> 6;     // 0..3
    const int lane = threadIdx.x & 63;
    const bool is_f = (wid < 2);

    float wreg[6];
    float wv[140];   // VGPR pin
    float av[240];   // AGPR pin
    if (is_f) {
#pragma unroll
        for (int r = 0; r < 6; ++r) {
            const int idx = r * 64 + lane;
            float v = 0.f;
            if      (idx < 100) v = Wh1[idx];
            else if (idx < 150) v = bh1[idx - 100];
            else if (idx < 270) v = Wh2[880 + (idx - 150)];   // rows 44..49
            else if (idx < 290) v = bh2[idx - 270];
            else if (idx < 330) v = Wh3[idx - 290];
            else if (idx < 332) v = bh3[idx - 330];
            wreg[r] = v;
        }
#pragma unroll
        for (int i = 0; i < 240; ++i) {        // AGPR pin: Wh2 rows 25..36
            av[i] = Wh2[500 + i];
            asm volatile("" : "+a"(av[i]));
        }
#pragma unroll
        for (int i = 0; i < 140; ++i) {        // VGPR pin: Wh2 rows 37..43
            wv[i] = Wh2[740 + i];
            asm volatile("" : "+v"(wv[i]));
        }
    } else {
#pragma unroll
        for (int r = 0; r < 6; ++r) {
            const int idx = r * 64 + lane;
            float v = 0.f;
            if      (idx < 80)  v = Wx2[920 + idx];           // rows 46..49
            else if (idx < 100) v = bx2[idx - 80];
            else if (idx < 140) v = Wx3[idx - 100];
            else if (idx < 142) v = bx3[idx - 140];
            wreg[r] = v;
        }
#pragma unroll
        for (int i = 0; i < 240; ++i) {        // AGPR pin: Wx2 rows 27..38
            av[i] = Wx2[540 + i];
            asm volatile("" : "+a"(av[i]));
        }
#pragma unroll
        for (int i = 0; i < 140; ++i) {        // VGPR pin: Wx2 rows 39..45
            wv[i] = Wx2[780 + i];
            asm volatile("" : "+v"(wv[i]));
        }
    }
    __syncthreads();

    const int lw = is_f ? wid : (wid - 2);
    const int lpA = lw * 128 + lane;
    const int lpB = lpA + 64;
    const int pA  = blockIdx.x * 256 + lpA;
    const int pB  = blockIdx.x * 256 + lpB;

    float hA0 = 0.f, hA1 = 0.f, hB0 = 0.f, hB1 = 0.f;
    if (is_f) {
        hA0 = w[2 * pA]; hA1 = w[2 * pA + 1];
        hB0 = w[2 * pB]; hB1 = w[2 * pB + 1];
    }
    float2* __restrict__ orowA = out + (size_t)pA * (size_t)T;
    float2* __restrict__ orowB = out + (size_t)pB * (size_t)T;

    for (int t = 0; t <= T; ++t) {
        if (is_f) {
            if (t < T) {
                // ===== F: h = lrelu3(h), 2 points, broadcasts shared =====
                float a1A[50], a1B[50];
#pragma unroll
                for (int j = 0; j < 50; ++j) {
                    const float s0 = WQ(j), s1 = WQ(50 + j), sb = WQ(100 + j);
                    a1A[j] = lrelu(fmaf(hA0, s0, fmaf(hA1, s1, sb)));
                    a1B[j] = lrelu(fmaf(hB0, s0, fmaf(hB1, s1, sb)));
                }
                float accA[20], accB[20];
#pragma unroll
                for (int c = 0; c < 20; ++c) {
                    const float bv = WQ(270 + c);
                    accA[c] = bv; accB[c] = bv;
                }
#pragma unroll
                for (int k = 0; k < 25; ++k) {          // rows 0..24 via LDS
                    const float akA = a1A[k], akB = a1B[k];
#pragma unroll
                    for (int c = 0; c < 5; ++c) {
                        const float4 v = sW2h[k * 5 + c];
                        accA[4*c+0] = fmaf(akA, v.x, accA[4*c+0]);
                        accA[4*c+1] = fmaf(akA, v.y, accA[4*c+1]);
                        accA[4*c+2] = fmaf(akA, v.z, accA[4*c+2]);
                        accA[4*c+3] = fmaf(akA, v.w, accA[4*c+3]);
                        accB[4*c+0] = fmaf(akB, v.x, accB[4*c+0]);
                        accB[4*c+1] = fmaf(akB, v.y, accB[4*c+1]);
                        accB[4*c+2] = fmaf(akB, v.z, accB[4*c+2]);
                        accB[4*c+3] = fmaf(akB, v.w, accB[4*c+3]);
                    }
                }
#pragma unroll
                for (int k = 25; k < 37; ++k) {         // rows 25..36 via AGPR
                    const float akA = a1A[k], akB = a1B[k];
#pragma unroll
                    for (int c = 0; c < 20; ++c) {
                        const float wvv = av[(k - 25) * 20 + c];
                        accA[c] = fmaf(akA, wvv, accA[c]);
                        accB[c] = fmaf(akB, wvv, accB[c]);
                    }
                }
#pragma unroll
                for (int k = 37; k < 44; ++k) {         // rows 37..43 via VGPR
                    const float akA = a1A[k], akB = a1B[k];
#pragma unroll
                    for (int c = 0; c < 20; ++c) {
                        const float wvv = wv[(k - 37) * 20 + c];
                        accA[c] = fmaf(akA, wvv, accA[c]);
                        accB[c] = fmaf(akB, wvv, accB[c]);
                    }
                }
#pragma unroll
                for (int k = 44; k < 50; ++k) {         // rows 44..49 via RL
                    const float akA = a1A[k], akB = a1B[k];
#pragma unroll
                    for (int c = 0; c < 20; ++c) {
                        const float wvv = WQ(150 + (k - 44) * 20 + c);
                        accA[c] = fmaf(akA, wvv, accA[c]);
                        accB[c] = fmaf(akB, wvv, accB[c]);
                    }
                }
                float zA0 = WQ(330), zA1 = WQ(331);
                float zB0 = zA0, zB1 = zA1;
#pragma unroll
                for (int k = 0; k < 20; ++k) {
                    const float wx = WQ(290 + 2 * k), wy = WQ(291 + 2 * k);
                    const float eA = lrelu(accA[k]), eB = lrelu(accB[k]);
                    zA0 = fmaf(eA, wx, zA0); zA1 = fmaf(eA, wy, zA1);
                    zB0 = fmaf(eB, wx, zB0); zB1 = fmaf(eB, wy, zB1);
                }
                hA0 = lrelu(zA0); hA1 = lrelu(zA1);
                hB0 = lrelu(zB0); hB1 = lrelu(zB1);

                hbuf[t & 1][lpA] = make_float2(hA0, hA1);
                hbuf[t & 1][lpB] = make_float2(hB0, hB1);
            }
        } else {
            if (t > 0) {
                // ===== X: x_s = sig3(h_s), s = t-1, 2 points =====
                const int s = t - 1;
                const float2 hvA = hbuf[s & 1][lpA];
                const float2 hvB = hbuf[s & 1][lpB];

                float accA[20], accB[20];
#pragma unroll
                for (int c = 0; c < 20; ++c) {
                    const float bv = WQ(80 + c);
                    accA[c] = bv; accB[c] = bv;
                }
#pragma unroll
                for (int k = 0; k < 50; ++k) {
                    const float4 l1 = sL1x[k];           // Wx1-trip via LDS
                    const float xkA = sigf(fmaf(hvA.x, l1.x, fmaf(hvA.y, l1.y, l1.z)));
                    const float xkB = sigf(fmaf(hvB.x, l1.x, fmaf(hvB.y, l1.y, l1.z)));
                    if (k < 27) {                        // rows 0..26 via LDS
#pragma unroll
                        for (int c = 0; c < 5; ++c) {
                            const float4 v = sW2x[k * 5 + c];
                            accA[4*c+0] = fmaf(xkA, v.x, accA[4*c+0]);
                            accA[4*c+1] = fmaf(xkA, v.y, accA[4*c+1]);
                            accA[4*c+2] = fmaf(xkA, v.z, accA[4*c+2]);
                            accA[4*c+3] = fmaf(xkA, v.w, accA[4*c+3]);
                            accB[4*c+0] = fmaf(xkB, v.x, accB[4*c+0]);
                            accB[4*c+1] = fmaf(xkB, v.y, accB[4*c+1]);
                            accB[4*c+2] = fmaf(xkB, v.z, accB[4*c+2]);
                            accB[4*c+3] = fmaf(xkB, v.w, accB[4*c+3]);
                        }
                    } else if (k < 39) {                 // rows 27..38 via AGPR
#pragma unroll
                        for (int c = 0; c < 20; ++c) {
                            const float wvv = av[(k - 27) * 20 + c];
                            accA[c] = fmaf(xkA, wvv, accA[c]);
                            accB[c] = fmaf(xkB, wvv, accB[c]);
                        }
                    } else if (k < 46) {                 // rows 39..45 via VGPR
#pragma unroll
                        for (int c = 0; c < 20; ++c) {
                            const float wvv = wv[(k - 39) * 20 + c];
                            accA[c] = fmaf(xkA, wvv, accA[c]);
                            accB[c] = fmaf(xkB, wvv, accB[c]);
                        }
                    } else {                             // rows 46..49 via RL
#pragma unroll
                        for (int c = 0; c < 20; ++c) {
                            const float wvv = WQ((k - 46) * 20 + c);
                            accA[c] = fmaf(xkA, wvv, accA[c]);
                            accB[c] = fmaf(xkB, wvv, accB[c]);
                        }
                    }
                }
                float zA0 = WQ(140), zA1 = WQ(141);
                float zB0 = zA0, zB1 = zA1;
#pragma unroll
                for (int k = 0; k < 20; ++k) {
                    const float wx = WQ(100 + 2 * k), wy = WQ(101 + 2 * k);
                    const float eA = sigf(accA[k]), eB = sigf(accB[k]);
                    zA0 = fmaf(eA, wx, zA0); zA1 = fmaf(eA, wy, zA1);
                    zB0 = fmaf(eB, wx, zB0); zB1 = fmaf(eB, wy, zB1);
                }
                orowA[s] = make_float2(sigf(zA0), sigf(zA1));
                orowB[s] = make_float2(sigf(zB0), sigf(zB1));
            }
        }
        __syncthreads();   // orders hbuf write (iter t) -> read (iter t+1)
    }
}

extern "C" void kernel_launch(void* const* d_in, const int* in_sizes, int n_in,
                              void* d_out, int out_size, void* d_ws, size_t ws_size,
                              hipStream_t stream)
{
    const float* w   = (const float*)d_in[0];
    const float* Wh1 = (const float*)d_in[1];
    const float* bh1 = (const float*)d_in[2];
    const float* Wh2 = (const float*)d_in[3];
    const float* bh2 = (const float*)d_in[4];
    const float* Wh3 = (const float*)d_in[5];
    const float* bh3 = (const float*)d_in[6];
    const float* Wx1 = (const float*)d_in[7];
    const float* bx1 = (const float*)d_in[8];
    const float* Wx2 = (const float*)d_in[9];
    const float* bx2 = (const float*)d_in[10];
    const float* Wx3 = (const float*)d_in[11];
    const float* bx3 = (const float*)d_in[12];

    const int B = in_sizes[0] / 2;        // 65536 (divisible by 256)
    const int T = out_size / (B * 2);     // 512

    pc6_kernel<<<B / 256, 256, 0, stream>>>(
        w, Wh1, bh1, Wh2, bh2, Wh3, bh3,
        Wx1, bx1, Wx2, bx2, Wx3, bx3,
        (float2*)d_out, B, T);
}

// Round 27
// 3966.599 us; speedup vs baseline: 8.4236x; 8.4236x over previous
//
#include <hip/hip_runtime.h>

#define LOG2E 1.44269504088896340736f

__device__ __forceinline__ float lrelu(float z) { return fmaxf(z, 0.01f * z); }
__device__ __forceinline__ float sigf(float z) {
    float p = __builtin_amdgcn_exp2f(-LOG2E * z);
    return __builtin_amdgcn_rcpf(1.0f + p);
}

#define WQ(i) __int_as_float(__builtin_amdgcn_readlane(__float_as_int(wreg[(i) >> 6]), (i) & 63))

// ====== PC-v7: R25 structure; "pin" rows -> explicit uniform L2 loads ======
// R26: AGPR pin spilled (VGPR 256, FETCH 23GB). R25 post-hoc: its 140-float
// "VGPR pin" actually became per-step uniform L2 loads (VGPR=116, FETCH flat,
// perf improved) — i.e. the THIRD pipe (scalar/vector memory) carries weight
// traffic for free at this volume (R16's failure was 2528 floats; 140 fine).
// Tri-pipe split: RL->VALU 8cyc/f, ds_read->LDS 12cyc/f4 (CU-shared),
// uniform L2 loads->mem pipe (cheap). Extend L2 share moderately:
//   F: LDS Wh2 rows 0..36 | L2 rows 37..49 (260) | RL 212:
//      0..99 Wh1 | 100..149 bh1 | 150..169 bh2 | 170..209 Wh3 | 210..211 bh3
//   X: LDS Wx2 rows 0..38 + Wx1-trip | L2 rows 39..49 (220) | RL 62:
//      0..19 bx2 | 20..59 Wx3 | 60..61 bx3
__global__ void __launch_bounds__(256, 1)
pc7_kernel(const float* __restrict__ w,
           const float* __restrict__ Wh1, const float* __restrict__ bh1,
           const float* __restrict__ Wh2, const float* __restrict__ bh2,
           const float* __restrict__ Wh3, const float* __restrict__ bh3,
           const float* __restrict__ Wx1, const float* __restrict__ bx1,
           const float* __restrict__ Wx2, const float* __restrict__ bx2,
           const float* __restrict__ Wx3, const float* __restrict__ bx3,
           float2* __restrict__ out, int B, int T)
{
    __shared__ float4 sW2h[185];       // Wh2 rows 0..36
    __shared__ float4 sW2x[195];       // Wx2 rows 0..38
    __shared__ float4 sL1x[50];        // (Wx1[0][k], Wx1[1][k], bx1[k], 0)
    __shared__ float2 hbuf[2][256];    // double-buffered h handoff

    {
        float* a = (float*)sW2h;
        for (int i = threadIdx.x; i < 740; i += 256) a[i] = Wh2[i];
        float* b = (float*)sW2x;
        for (int i = threadIdx.x; i < 780; i += 256) b[i] = Wx2[i];
        if (threadIdx.x < 50)
            sL1x[threadIdx.x] = make_float4(Wx1[threadIdx.x], Wx1[50 + threadIdx.x],
                                            bx1[threadIdx.x], 0.f);
    }

    const int wid  = threadIdx.x >> 6;     // 0..3
    const int lane = threadIdx.x & 63;
    const bool is_f = (wid < 2);

    float wreg[4];
    if (is_f) {
#pragma unroll
        for (int r = 0; r < 4; ++r) {
            const int idx = r * 64 + lane;
            float v = 0.f;
            if      (idx < 100) v = Wh1[idx];
            else if (idx < 150) v = bh1[idx - 100];
            else if (idx < 170) v = bh2[idx - 150];
            else if (idx < 210) v = Wh3[idx - 170];
            else if (idx < 212) v = bh3[idx - 210];
            wreg[r] = v;
        }
    } else {
#pragma unroll
        for (int r = 0; r < 4; ++r) {
            const int idx = r * 64 + lane;
            float v = 0.f;
            if      (idx < 20) v = bx2[idx];
            else if (idx < 60) v = Wx3[idx - 20];
            else if (idx < 62) v = bx3[idx - 60];
            wreg[r] = v;
        }
    }
    __syncthreads();

    const int lw = is_f ? wid : (wid - 2);
    const int lpA = lw * 128 + lane;
    const int lpB = lpA + 64;
    const int pA  = blockIdx.x * 256 + lpA;
    const int pB  = blockIdx.x * 256 + lpB;

    float hA0 = 0.f, hA1 = 0.f, hB0 = 0.f, hB1 = 0.f;
    if (is_f) {
        hA0 = w[2 * pA]; hA1 = w[2 * pA + 1];
        hB0 = w[2 * pB]; hB1 = w[2 * pB + 1];
    }
    float2* __restrict__ orowA = out + (size_t)pA * (size_t)T;
    float2* __restrict__ orowB = out + (size_t)pB * (size_t)T;

    // uniform L2-resident row pointers
    const float* __restrict__ gWh2 = Wh2 + 740;   // rows 37..49
    const float* __restrict__ gWx2 = Wx2 + 780;   // rows 39..49

    for (int t = 0; t <= T; ++t) {
        if (is_f) {
            if (t < T) {
                // ===== F: h = lrelu3(h), 2 points, broadcasts shared =====
                float a1A[50], a1B[50];
#pragma unroll
                for (int j = 0; j < 50; ++j) {
                    const float s0 = WQ(j), s1 = WQ(50 + j), sb = WQ(100 + j);
                    a1A[j] = lrelu(fmaf(hA0, s0, fmaf(hA1, s1, sb)));
                    a1B[j] = lrelu(fmaf(hB0, s0, fmaf(hB1, s1, sb)));
                }
                float accA[20], accB[20];
#pragma unroll
                for (int c = 0; c < 20; ++c) {
                    const float bv = WQ(150 + c);
                    accA[c] = bv; accB[c] = bv;
                }
#pragma unroll
                for (int k = 0; k < 37; ++k) {          // rows 0..36 via LDS
                    const float akA = a1A[k], akB = a1B[k];
#pragma unroll
                    for (int c = 0; c < 5; ++c) {
                        const float4 v = sW2h[k * 5 + c];
                        accA[4*c+0] = fmaf(akA, v.x, accA[4*c+0]);
                        accA[4*c+1] = fmaf(akA, v.y, accA[4*c+1]);
                        accA[4*c+2] = fmaf(akA, v.z, accA[4*c+2]);
                        accA[4*c+3] = fmaf(akA, v.w, accA[4*c+3]);
                        accB[4*c+0] = fmaf(akB, v.x, accB[4*c+0]);
                        accB[4*c+1] = fmaf(akB, v.y, accB[4*c+1]);
                        accB[4*c+2] = fmaf(akB, v.z, accB[4*c+2]);
                        accB[4*c+3] = fmaf(akB, v.w, accB[4*c+3]);
                    }
                }
#pragma unroll
                for (int k = 37; k < 50; ++k) {         // rows 37..49 via L2
                    const float akA = a1A[k], akB = a1B[k];
#pragma unroll
                    for (int c = 0; c < 20; ++c) {
                        const float wvv = gWh2[(k - 37) * 20 + c];
                        accA[c] = fmaf(akA, wvv, accA[c]);
                        accB[c] = fmaf(akB, wvv, accB[c]);
                    }
                }
                float zA0 = WQ(210), zA1 = WQ(211);
                float zB0 = zA0, zB1 = zA1;
#pragma unroll
                for (int k = 0; k < 20; ++k) {
                    const float wx = WQ(170 + 2 * k), wy = WQ(171 + 2 * k);
                    const float eA = lrelu(accA[k]), eB = lrelu(accB[k]);
                    zA0 = fmaf(eA, wx, zA0); zA1 = fmaf(eA, wy, zA1);
                    zB0 = fmaf(eB, wx, zB0); zB1 = fmaf(eB, wy, zB1);
                }
                hA0 = lrelu(zA0); hA1 = lrelu(zA1);
                hB0 = lrelu(zB0); hB1 = lrelu(zB1);

                hbuf[t & 1][lpA] = make_float2(hA0, hA1);
                hbuf[t & 1][lpB] = make_float2(hB0, hB1);
            }
        } else {
            if (t > 0) {
                // ===== X: x_s = sig3(h_s), s = t-1, 2 points =====
                const int s = t - 1;
                const float2 hvA = hbuf[s & 1][lpA];
                const float2 hvB = hbuf[s & 1][lpB];

                float accA[20], accB[20];
#pragma unroll
                for (int c = 0; c < 20; ++c) {
                    const float bv = WQ(c);
                    accA[c] = bv; accB[c] = bv;
                }
#pragma unroll
                for (int k = 0; k < 50; ++k) {
                    const float4 l1 = sL1x[k];           // Wx1-trip via LDS
                    const float xkA = sigf(fmaf(hvA.x, l1.x, fmaf(hvA.y, l1.y, l1.z)));
                    const float xkB = sigf(fmaf(hvB.x, l1.x, fmaf(hvB.y, l1.y, l1.z)));
                    if (k < 39) {                        // rows 0..38 via LDS
#pragma unroll
                        for (int c = 0; c < 5; ++c) {
                            const float4 v = sW2x[k * 5 + c];
                            accA[4*c+0] = fmaf(xkA, v.x, accA[4*c+0]);
                            accA[4*c+1] = fmaf(xkA, v.y, accA[4*c+1]);
                            accA[4*c+2] = fmaf(xkA, v.z, accA[4*c+2]);
                            accA[4*c+3] = fmaf(xkA, v.w, accA[4*c+3]);
                            accB[4*c+0] = fmaf(xkB, v.x, accB[4*c+0]);
                            accB[4*c+1] = fmaf(xkB, v.y, accB[4*c+1]);
                            accB[4*c+2] = fmaf(xkB, v.z, accB[4*c+2]);
                            accB[4*c+3] = fmaf(xkB, v.w, accB[4*c+3]);
                        }
                    } else {                             // rows 39..49 via L2
#pragma unroll
                        for (int c = 0; c < 20; ++c) {
                            const float wvv = gWx2[(k - 39) * 20 + c];
                            accA[c] = fmaf(xkA, wvv, accA[c]);
                            accB[c] = fmaf(xkB, wvv, accB[c]);
                        }
                    }
                }
                float zA0 = WQ(60), zA1 = WQ(61);
                float zB0 = zA0, zB1 = zA1;
#pragma unroll
                for (int k = 0; k < 20; ++k) {
                    const float wx = WQ(20 + 2 * k), wy = WQ(21 + 2 * k);
                    const float eA = sigf(accA[k]), eB = sigf(accB[k]);
                    zA0 = fmaf(eA, wx, zA0); zA1 = fmaf(eA, wy, zA1);
                    zB0 = fmaf(eB, wx, zB0); zB1 = fmaf(eB, wy, zB1);
                }
                orowA[s] = make_float2(sigf(zA0), sigf(zA1));
                orowB[s] = make_float2(sigf(zB0), sigf(zB1));
            }
        }
        __syncthreads();   // orders hbuf write (iter t) -> read (iter t+1)
    }
}

extern "C" void kernel_launch(void* const* d_in, const int* in_sizes, int n_in,
                              void* d_out, int out_size, void* d_ws, size_t ws_size,
                              hipStream_t stream)
{
    const float* w   = (const float*)d_in[0];
    const float* Wh1 = (const float*)d_in[1];
    const float* bh1 = (const float*)d_in[2];
    const float* Wh2 = (const float*)d_in[3];
    const float* bh2 = (const float*)d_in[4];
    const float* Wh3 = (const float*)d_in[5];
    const float* bh3 = (const float*)d_in[6];
    const float* Wx1 = (const float*)d_in[7];
    const float* bx1 = (const float*)d_in[8];
    const float* Wx2 = (const float*)d_in[9];
    const float* bx2 = (const float*)d_in[10];
    const float* Wx3 = (const float*)d_in[11];
    const float* bx3 = (const float*)d_in[12];

    const int B = in_sizes[0] / 2;        // 65536 (divisible by 256)
    const int T = out_size / (B * 2);     // 512

    pc7_kernel<<<B / 256, 256, 0, stream>>>(
        w, Wh1, bh1, Wh2, bh2, Wh3, bh3,
        Wx1, bx1, Wx2, bx2, Wx3, bx3,
        (float2*)d_out, B, T);
}

// Round 28
// 3530.771 us; speedup vs baseline: 9.4634x; 1.1234x over previous
//
#include <hip/hip_runtime.h>

#define LOG2E 1.44269504088896340736f

__device__ __forceinline__ float lrelu(float z) { return fmaxf(z, 0.01f * z); }
__device__ __forceinline__ float sigf(float z) {
    float p = __builtin_amdgcn_exp2f(-LOG2E * z);
    return __builtin_amdgcn_rcpf(1.0f + p);
}

#define WQ(i) __int_as_float(__builtin_amdgcn_readlane(__float_as_int(wreg[(i) >> 6]), (i) & 63))

// ====== PC-v8: R25 exactly, except X's Wx1-trip moves LDS -> readlane ======
// R27 lesson: dropping the "+v" pin + growing L2 share regressed (4.19 vs
// 3.55) — R25's partial pin (~68 resident floats, VGPR 116) was real.
// R25 pipe model: LDS 860 f4 x 12 = 10.3K cyc/CU-step (BINDING); F VALU
// 7.5K; X VALU 6.3K. Single variable: Wx1-trip (50 f4/step/wave) off the
// binding LDS pipe onto X's idle VALU (RL +150 floats): LDS -> ~9.1K,
// X VALU -> ~7.5K — three pipes balanced.
//   F wreg(332): 0..99 Wh1 | 100..149 bh1 | 150..269 Wh2 rows 44..49
//                | 270..289 bh2 | 290..329 Wh3 | 330..331 bh3
//   F pin(140):  Wh2 rows 37..43   F LDS: Wh2 rows 0..36 (185 f4)
//   X wreg(292): 0..99 Wx1 | 100..149 bx1 | 150..229 Wx2 rows 46..49
//                | 230..249 bx2 | 250..289 Wx3 | 290..291 bx3
//   X pin(140):  Wx2 rows 39..45   X LDS: Wx2 rows 0..38 (195 f4)
__global__ void __launch_bounds__(256, 1)
pc8_kernel(const float* __restrict__ w,
           const float* __restrict__ Wh1, const float* __restrict__ bh1,
           const float* __restrict__ Wh2, const float* __restrict__ bh2,
           const float* __restrict__ Wh3, const float* __restrict__ bh3,
           const float* __restrict__ Wx1, const float* __restrict__ bx1,
           const float* __restrict__ Wx2, const float* __restrict__ bx2,
           const float* __restrict__ Wx3, const float* __restrict__ bx3,
           float2* __restrict__ out, int B, int T)
{
    __shared__ float4 sW2h[185];       // Wh2 rows 0..36
    __shared__ float4 sW2x[195];       // Wx2 rows 0..38
    __shared__ float2 hbuf[2][256];    // double-buffered h handoff

    {
        float* a = (float*)sW2h;
        for (int i = threadIdx.x; i < 740; i += 256) a[i] = Wh2[i];
        float* b = (float*)sW2x;
        for (int i = threadIdx.x; i < 780; i += 256) b[i] = Wx2[i];
    }

    const int wid  = threadIdx.x >> 6;     // 0..3
    const int lane = threadIdx.x & 63;
    const bool is_f = (wid < 2);

    float wreg[6];
    float wv[140];   // partial VGPR pin (R25 mechanism)
    if (is_f) {
#pragma unroll
        for (int r = 0; r < 6; ++r) {
            const int idx = r * 64 + lane;
            float v = 0.f;
            if      (idx < 100) v = Wh1[idx];
            else if (idx < 150) v = bh1[idx - 100];
            else if (idx < 270) v = Wh2[880 + (idx - 150)];   // rows 44..49
            else if (idx < 290) v = bh2[idx - 270];
            else if (idx < 330) v = Wh3[idx - 290];
            else if (idx < 332) v = bh3[idx - 330];
            wreg[r] = v;
        }
#pragma unroll
        for (int i = 0; i < 140; ++i) {        // pin Wh2 rows 37..43
            wv[i] = Wh2[740 + i];
            asm volatile("" : "+v"(wv[i]));
        }
    } else {
#pragma unroll
        for (int r = 0; r < 6; ++r) {
            const int idx = r * 64 + lane;
            float v = 0.f;
            if      (idx < 100) v = Wx1[idx];
            else if (idx < 150) v = bx1[idx - 100];
            else if (idx < 230) v = Wx2[920 + (idx - 150)];   // rows 46..49
            else if (idx < 250) v = bx2[idx - 230];
            else if (idx < 290) v = Wx3[idx - 250];
            else if (idx < 292) v = bx3[idx - 290];
            wreg[r] = v;
        }
#pragma unroll
        for (int i = 0; i < 140; ++i) {        // pin Wx2 rows 39..45
            wv[i] = Wx2[780 + i];
            asm volatile("" : "+v"(wv[i]));
        }
    }
    __syncthreads();

    const int lw = is_f ? wid : (wid - 2);
    const int lpA = lw * 128 + lane;
    const int lpB = lpA + 64;
    const int pA  = blockIdx.x * 256 + lpA;
    const int pB  = blockIdx.x * 256 + lpB;

    float hA0 = 0.f, hA1 = 0.f, hB0 = 0.f, hB1 = 0.f;
    if (is_f) {
        hA0 = w[2 * pA]; hA1 = w[2 * pA + 1];
        hB0 = w[2 * pB]; hB1 = w[2 * pB + 1];
    }
    float2* __restrict__ orowA = out + (size_t)pA * (size_t)T;
    float2* __restrict__ orowB = out + (size_t)pB * (size_t)T;

    for (int t = 0; t <= T; ++t) {
        if (is_f) {
            if (t < T) {
                // ===== F: h = lrelu3(h), 2 points, broadcasts shared =====
                float a1A[50], a1B[50];
#pragma unroll
                for (int j = 0; j < 50; ++j) {
                    const float s0 = WQ(j), s1 = WQ(50 + j), sb = WQ(100 + j);
                    a1A[j] = lrelu(fmaf(hA0, s0, fmaf(hA1, s1, sb)));
                    a1B[j] = lrelu(fmaf(hB0, s0, fmaf(hB1, s1, sb)));
                }
                float accA[20], accB[20];
#pragma unroll
                for (int c = 0; c < 20; ++c) {
                    const float bv = WQ(270 + c);
                    accA[c] = bv; accB[c] = bv;
                }
#pragma unroll
                for (int k = 0; k < 37; ++k) {          // rows 0..36 via LDS
                    const float akA = a1A[k], akB = a1B[k];
#pragma unroll
                    for (int c = 0; c < 5; ++c) {
                        const float4 v = sW2h[k * 5 + c];
                        accA[4*c+0] = fmaf(akA, v.x, accA[4*c+0]);
                        accA[4*c+1] = fmaf(akA, v.y, accA[4*c+1]);
                        accA[4*c+2] = fmaf(akA, v.z, accA[4*c+2]);
                        accA[4*c+3] = fmaf(akA, v.w, accA[4*c+3]);
                        accB[4*c+0] = fmaf(akB, v.x, accB[4*c+0]);
                        accB[4*c+1] = fmaf(akB, v.y, accB[4*c+1]);
                        accB[4*c+2] = fmaf(akB, v.z, accB[4*c+2]);
                        accB[4*c+3] = fmaf(akB, v.w, accB[4*c+3]);
                    }
                }
#pragma unroll
                for (int k = 37; k < 44; ++k) {         // rows 37..43 via pin
                    const float akA = a1A[k], akB = a1B[k];
#pragma unroll
                    for (int c = 0; c < 20; ++c) {
                        const float wvv = wv[(k - 37) * 20 + c];
                        accA[c] = fmaf(akA, wvv, accA[c]);
                        accB[c] = fmaf(akB, wvv, accB[c]);
                    }
                }
#pragma unroll
                for (int k = 44; k < 50; ++k) {         // rows 44..49 via RL
                    const float akA = a1A[k], akB = a1B[k];
#pragma unroll
                    for (int c = 0; c < 20; ++c) {
                        const float wvv = WQ(150 + (k - 44) * 20 + c);
                        accA[c] = fmaf(akA, wvv, accA[c]);
                        accB[c] = fmaf(akB, wvv, accB[c]);
                    }
                }
                float zA0 = WQ(330), zA1 = WQ(331);
                float zB0 = zA0, zB1 = zA1;
#pragma unroll
                for (int k = 0; k < 20; ++k) {
                    const float wx = WQ(290 + 2 * k), wy = WQ(291 + 2 * k);
                    const float eA = lrelu(accA[k]), eB = lrelu(accB[k]);
                    zA0 = fmaf(eA, wx, zA0); zA1 = fmaf(eA, wy, zA1);
                    zB0 = fmaf(eB, wx, zB0); zB1 = fmaf(eB, wy, zB1);
                }
                hA0 = lrelu(zA0); hA1 = lrelu(zA1);
                hB0 = lrelu(zB0); hB1 = lrelu(zB1);

                hbuf[t & 1][lpA] = make_float2(hA0, hA1);
                hbuf[t & 1][lpB] = make_float2(hB0, hB1);
            }
        } else {
            if (t > 0) {
                // ===== X: x_s = sig3(h_s), s = t-1, 2 points =====
                const int s = t - 1;
                const float2 hvA = hbuf[s & 1][lpA];
                const float2 hvB = hbuf[s & 1][lpB];

                float accA[20], accB[20];
#pragma unroll
                for (int c = 0; c < 20; ++c) {
                    const float bv = WQ(230 + c);
                    accA[c] = bv; accB[c] = bv;
                }
#pragma unroll
                for (int k = 0; k < 50; ++k) {
                    // Wx1-trip via RL (off the binding LDS pipe)
                    const float s0 = WQ(k), s1 = WQ(50 + k), sb = WQ(100 + k);
                    const float xkA = sigf(fmaf(hvA.x, s0, fmaf(hvA.y, s1, sb)));
                    const float xkB = sigf(fmaf(hvB.x, s0, fmaf(hvB.y, s1, sb)));
                    if (k < 39) {                        // rows 0..38 via LDS
#pragma unroll
                        for (int c = 0; c < 5; ++c) {
                            const float4 v = sW2x[k * 5 + c];
                            accA[4*c+0] = fmaf(xkA, v.x, accA[4*c+0]);
                            accA[4*c+1] = fmaf(xkA, v.y, accA[4*c+1]);
                            accA[4*c+2] = fmaf(xkA, v.z, accA[4*c+2]);
                            accA[4*c+3] = fmaf(xkA, v.w, accA[4*c+3]);
                            accB[4*c+0] = fmaf(xkB, v.x, accB[4*c+0]);
                            accB[4*c+1] = fmaf(xkB, v.y, accB[4*c+1]);
                            accB[4*c+2] = fmaf(xkB, v.z, accB[4*c+2]);
                            accB[4*c+3] = fmaf(xkB, v.w, accB[4*c+3]);
                        }
                    } else if (k < 46) {                 // rows 39..45 via pin
#pragma unroll
                        for (int c = 0; c < 20; ++c) {
                            const float wvv = wv[(k - 39) * 20 + c];
                            accA[c] = fmaf(xkA, wvv, accA[c]);
                            accB[c] = fmaf(xkB, wvv, accB[c]);
                        }
                    } else {                             // rows 46..49 via RL
#pragma unroll
                        for (int c = 0; c < 20; ++c) {
                            const float wvv = WQ(150 + (k - 46) * 20 + c);
                            accA[c] = fmaf(xkA, wvv, accA[c]);
                            accB[c] = fmaf(xkB, wvv, accB[c]);
                        }
                    }
                }
                float zA0 = WQ(290), zA1 = WQ(291);
                float zB0 = zA0, zB1 = zA1;
#pragma unroll
                for (int k = 0; k < 20; ++k) {
                    const float wx = WQ(250 + 2 * k), wy = WQ(251 + 2 * k);
                    const float eA = sigf(accA[k]), eB = sigf(accB[k]);
                    zA0 = fmaf(eA, wx, zA0); zA1 = fmaf(eA, wy, zA1);
                    zB0 = fmaf(eB, wx, zB0); zB1 = fmaf(eB, wy, zB1);
                }
                orowA[s] = make_float2(sigf(zA0), sigf(zA1));
                orowB[s] = make_float2(sigf(zB0), sigf(zB1));
            }
        }
        __syncthreads();   // orders hbuf write (iter t) -> read (iter t+1)
    }
}

extern "C" void kernel_launch(void* const* d_in, const int* in_sizes, int n_in,
                              void* d_out, int out_size, void* d_ws, size_t ws_size,
                              hipStream_t stream)
{
    const float* w   = (const float*)d_in[0];
    const float* Wh1 = (const float*)d_in[1];
    const float* bh1 = (const float*)d_in[2];
    const float* Wh2 = (const float*)d_in[3];
    const float* bh2 = (const float*)d_in[4];
    const float* Wh3 = (const float*)d_in[5];
    const float* bh3 = (const float*)d_in[6];
    const float* Wx1 = (const float*)d_in[7];
    const float* bx1 = (const float*)d_in[8];
    const float* Wx2 = (const float*)d_in[9];
    const float* bx2 = (const float*)d_in[10];
    const float* Wx3 = (const float*)d_in[11];
    const float* bx3 = (const float*)d_in[12];

    const int B = in_sizes[0] / 2;        // 65536 (divisible by 256)
    const int T = out_size / (B * 2);     // 512

    pc8_kernel<<<B / 256, 256, 0, stream>>>(
        w, Wh1, bh1, Wh2, bh2, Wh3, bh3,
        Wx1, bx1, Wx2, bx2, Wx3, bx3,
        (float2*)d_out, B, T);
}